// Round 11
// baseline (278.566 us; speedup 1.0000x reference)
//
#include <hip/hip_runtime.h>
#include <math.h>
#include <stdint.h>

#define B_    4
#define NQ_   100
#define HW_   4096
#define D_    1024
#define H_    16
#define HD_   64
#define NCH_  2          // key chunks per (b,h) for split-K flash
#define KCH_  (HW_/NCH_) // 2048 keys per chunk
#define NT_   (KCH_/128) // 16 K-tiles per flash block
#define QT_   32         // queries per tile (4 tiles cover 100, padded)
#define MP_   512        // padded M for small GEMMs (400 -> 512)

typedef __attribute__((ext_vector_type(8))) short short8;
typedef __attribute__((ext_vector_type(8))) unsigned short ushort8v;
typedef __attribute__((ext_vector_type(4))) float f32x4;

// fp32 -> bf16 RNE
__device__ __forceinline__ unsigned short f2bf(float f) {
    unsigned int u = __float_as_uint(f);
    u += 0x7fffu + ((u >> 16) & 1u);
    return (unsigned short)(u >> 16);
}
__device__ __forceinline__ float bf2f(unsigned short h) {
    return __uint_as_float(((unsigned int)h) << 16);
}

// async global->LDS 16B (LDS ptr is wave-uniform base; HW adds lane*16B)
__device__ __forceinline__ void gl2lds16(const void* g, void* l) {
    typedef __attribute__((address_space(1))) unsigned int gu32;
    typedef __attribute__((address_space(3))) unsigned int lu32;
    __builtin_amdgcn_global_load_lds(
        reinterpret_cast<gu32*>(reinterpret_cast<uintptr_t>(g)),
        reinterpret_cast<lu32*>(reinterpret_cast<uintptr_t>(l)),
        16, 0, 0);
}

#define VMCNT0() asm volatile("s_waitcnt vmcnt(0)" ::: "memory")
#define BARRIER() do { __builtin_amdgcn_s_barrier(); \
                       __builtin_amdgcn_sched_barrier(0); } while (0)

// ---------------------------------------------------------------------------
// LayerNorm + bf16 helper: one wave handles one row. Rows >= real_rows
// write zeros (padding).
// ---------------------------------------------------------------------------
__device__ __forceinline__ void ln_row(
    const float* __restrict__ x, const float* __restrict__ g,
    const float* __restrict__ be, unsigned short* __restrict__ y,
    int row, int real_rows, int lane)
{
    unsigned short* yr = y + (size_t)row * D_;
    if (row >= real_rows) {
        #pragma unroll
        for (int k = 0; k < 4; ++k)
            *reinterpret_cast<ushort4*>(yr + lane*4 + k*256) = make_ushort4(0,0,0,0);
        return;
    }
    const float* xr = x + (size_t)row * D_;
    float4 v[4];
    float s = 0.f, ss = 0.f;
    #pragma unroll
    for (int k = 0; k < 4; ++k) {
        v[k] = *reinterpret_cast<const float4*>(xr + lane*4 + k*256);
        s  += v[k].x + v[k].y + v[k].z + v[k].w;
        ss += v[k].x*v[k].x + v[k].y*v[k].y + v[k].z*v[k].z + v[k].w*v[k].w;
    }
    #pragma unroll
    for (int o = 1; o < 64; o <<= 1) {
        s  += __shfl_xor(s,  o);
        ss += __shfl_xor(ss, o);
    }
    const float mu = s * (1.0f / D_);
    const float rs = rsqrtf(ss * (1.0f / D_) - mu*mu + 1e-5f);
    #pragma unroll
    for (int k = 0; k < 4; ++k) {
        const float4 gg = *reinterpret_cast<const float4*>(g  + lane*4 + k*256);
        const float4 bb = *reinterpret_cast<const float4*>(be + lane*4 + k*256);
        ushort4 o;
        o.x = f2bf((v[k].x - mu) * rs * gg.x + bb.x);
        o.y = f2bf((v[k].y - mu) * rs * gg.y + bb.y);
        o.z = f2bf((v[k].z - mu) * rs * gg.z + bb.z);
        o.w = f2bf((v[k].w - mu) * rs * gg.w + bb.w);
        *reinterpret_cast<ushort4*>(yr + lane*4 + k*256) = o;
    }
}

// ---------------------------------------------------------------------------
// Prep kernel (R11: hilo_w + mpack moved into the fused GEMM launch).
//   [0,    4096): ln_kv   (4 rows/block, 16384 rows)
//   [4096, 7168): wconv   in_w -> wfull_bf (float4/thread)
//   [7168, 7296): ln_q    (4 rows/block, 400 real of 512)
// ---------------------------------------------------------------------------
__global__ __launch_bounds__(256) void prep_kernel(
    const float* __restrict__ kv,   const float* __restrict__ g_kv,
    const float* __restrict__ b_kv, unsigned short* __restrict__ kvn,
    const float* __restrict__ qf,   const float* __restrict__ g_q,
    const float* __restrict__ b_q,  unsigned short* __restrict__ qn,
    const float* __restrict__ in_w, unsigned short* __restrict__ wfull)
{
    const int bid = blockIdx.x, tid = threadIdx.x;

    if (bid < 4096) {                       // ---- ln_kv
        ln_row(kv, g_kv, b_kv, kvn, bid*4 + (tid >> 6), B_*HW_, tid & 63);
    } else if (bid < 7168) {                // ---- wconv
        const int i = (bid - 4096)*256 + tid;
        const float4 v = reinterpret_cast<const float4*>(in_w)[i];
        ushort4 o;
        o.x = f2bf(v.x); o.y = f2bf(v.y); o.z = f2bf(v.z); o.w = f2bf(v.w);
        reinterpret_cast<ushort4*>(wfull)[i] = o;
    } else {                                // ---- ln_q
        ln_row(qf, g_q, b_q, qn, (bid - 7168)*4 + (tid >> 6), B_*NQ_, tid & 63);
    }
}

// ---------------------------------------------------------------------------
// R11 FUSED mega-GEMM launch, 3584 blocks:
//   [0,   1024): gemm_kv   (FROZEN R7 body, XCD swizzle on bid&7)
//   [1024,2048): Q-proj split-K (threads 0-255, K=1024/KS=128)
//   [2048,3072): hilo_w    out_w -> [hi|hi|lo] (tid<256)
//   [3072,3584): mpack     mask bits (red[] aliased onto dynamic LDS)
// The light blocks backfill CU slots while gemm_kv idles at barriers; they
// have no deps on prep outputs (read out_w/mask directly) and their outputs
// (wout, mp) are consumed only by later launches.
// WATCH: VGPR must stay <=64 for the gemm path (R6 spill lesson).
// ---------------------------------------------------------------------------
__global__ __launch_bounds__(512, 4) void gemm_kv_kernel(
    const unsigned short* __restrict__ A, const unsigned short* __restrict__ Wb,
    const float* __restrict__ bias, unsigned short* __restrict__ kp,
    unsigned short* __restrict__ vt,
    const unsigned short* __restrict__ qA, const unsigned short* __restrict__ qW,
    float* __restrict__ P,
    const float* __restrict__ out_w, unsigned short* __restrict__ wout,
    const int* __restrict__ mask, unsigned int* __restrict__ mp)
{
    extern __shared__ __align__(16) unsigned short lds[];

    const int tid  = threadIdx.x;       // 0..511
    const int wave = tid >> 6;          // 0..7
    const int lane = tid & 63;
    const int lr   = lane & 15, quad = lane >> 4;

    if (blockIdx.x >= 3072) {
        // ================= mpack path =================
        int* red = (int*)lds;                       // 8 ints
        const int mblk = blockIdx.x - 3072;         // 0..511
        const int qrow = mblk & 127, mb = mblk >> 7;
        unsigned int word = 0;
        if (qrow < NQ_ && tid < 128) {
            const int4* mr = reinterpret_cast<const int4*>(
                mask + ((size_t)(mb*NQ_ + qrow))*HW_ + tid*32);
            #pragma unroll
            for (int j = 0; j < 8; ++j) {
                const int4 v = mr[j];
                word |= (v.x!=0 ? 1u:0u) << (4*j);
                word |= (v.y!=0 ? 1u:0u) << (4*j+1);
                word |= (v.z!=0 ? 1u:0u) << (4*j+2);
                word |= (v.w!=0 ? 1u:0u) << (4*j+3);
            }
        }
        const int wany = __any(word != 0) ? 1 : 0;
        if (lane == 0) red[wave] = wany;
        __syncthreads();
        int hasany = 0;
        #pragma unroll
        for (int w = 0; w < 8; ++w) hasany |= red[w];
        if (tid < 128)
            mp[((size_t)(mb*128 + qrow))*128 + tid] = hasany ? word : 0xFFFFFFFFu;
        return;
    }
    if (blockIdx.x >= 2048) {
        // ================= hilo_w path =================
        if (tid < 256) {
            const int row = blockIdx.x - 2048;      // 0..1023
            const float4 v = reinterpret_cast<const float4*>(out_w + (size_t)row * D_)[tid];
            ushort4 hi, lo;
            hi.x = f2bf(v.x); hi.y = f2bf(v.y); hi.z = f2bf(v.z); hi.w = f2bf(v.w);
            lo.x = f2bf(v.x - bf2f(hi.x)); lo.y = f2bf(v.y - bf2f(hi.y));
            lo.z = f2bf(v.z - bf2f(hi.z)); lo.w = f2bf(v.w - bf2f(hi.w));
            unsigned short* yr = wout + (size_t)row * 3072;
            reinterpret_cast<ushort4*>(yr)[tid]        = hi;
            reinterpret_cast<ushort4*>(yr + 1024)[tid] = hi;
            reinterpret_cast<ushort4*>(yr + 2048)[tid] = lo;
        }
        return;
    }
    if (blockIdx.x >= 1024) {
        // ================= Q-proj split-K path =================
        const int bid2 = blockIdx.x - 1024;         // 0..1023
        const int bn = bid2 & 15, bm = (bid2 >> 4) & 7, sk = bid2 >> 7;
        unsigned short* As = lds;                    // 2048 elems
        unsigned short* Bs = lds + 2048;             // 2048 elems

        const int r0 = (tid & 255) >> 2;
        const int xs = (r0 & 3) ^ ((r0 >> 2) & 3);
        const int kc = (tid & 3) ^ xs;
        const unsigned short* ap = qA + (size_t)(bm*64 + r0)*1024 + sk*128 + kc*8;
        const unsigned short* bp = qW + (size_t)(bn*64 + r0)*1024 + sk*128 + kc*8;
        unsigned short* asd = As + (wave & 3)*512;
        unsigned short* bsd = Bs + (wave & 3)*512;

        f32x4 acc[4];
        #pragma unroll
        for (int j = 0; j < 4; ++j) acc[j] = (f32x4){0.f,0.f,0.f,0.f};

        const int arow = (wave & 3)*16 + lr;
        const int xa = (arow & 3) ^ ((arow >> 2) & 3);
        const int aoff = (arow*4 + (quad ^ xa))*8;
        int boff[4];
        #pragma unroll
        for (int j = 0; j < 4; ++j) {
            const int brow = j*16 + lr;
            const int xb = (brow & 3) ^ ((brow >> 2) & 3);
            boff[j] = (brow*4 + (quad ^ xb))*8;
        }

        #pragma unroll 1
        for (int s = 0; s < 4; ++s) {
            if (tid < 256) { gl2lds16(ap, asd); gl2lds16(bp, bsd); }
            ap += 32; bp += 32;
            __syncthreads();
            if (tid < 256) {
                const short8 af = *reinterpret_cast<const short8*>(&As[aoff]);
                short8 bf[4];
                #pragma unroll
                for (int j = 0; j < 4; ++j)
                    bf[j] = *reinterpret_cast<const short8*>(&Bs[boff[j]]);
                #pragma unroll
                for (int j = 0; j < 4; ++j)
                    acc[j] = __builtin_amdgcn_mfma_f32_16x16x32_bf16(af, bf[j], acc[j], 0, 0, 0);
            }
            __syncthreads();
        }

        if (tid < 256) {
            float* Pb = P + ((size_t)sk*MP_ + bm*64)*1024 + bn*64;
            const int m0 = (wave & 3)*16 + quad*4;
            #pragma unroll
            for (int j = 0; j < 4; ++j)
                #pragma unroll
                for (int r = 0; r < 4; ++r)
                    Pb[(size_t)(m0 + r)*1024 + j*16 + lr] = acc[j][r];
        }
        return;
    }

    // ================= gemm_kv path (FROZEN R7 body) =================
    const int wm2  = wave >> 2;         // 0..1  (M half: 64 rows)
    const int wn4  = wave & 3;          // 0..3  (N quarter: 64 cols)

    // XCD-range swizzle (bijective; 1024 blocks, 8 XCDs)
    const int x  = blockIdx.x & 7;
    const int g  = blockIdx.x >> 3;
    const int bm = x*16 + (g >> 3);     // 0..127  M tile (128 rows)
    const int bn = g & 7;               // 0..7    N tile (256 cols)

    // ---- staging source (pre-swizzled so linear LDS dest ends up swizzled)
    const int srow = tid >> 2;                           // 0..127
    const int sswz = (srow & 3) ^ ((srow >> 2) & 3);
    const int scol = ((tid & 3) ^ sswz) * 8;
    const unsigned short* aSrc  = A  + (size_t)(bm*128 + srow)*D_ + scol;
    const unsigned short* bSrc0 = Wb + (size_t)(bn*256 + srow)*D_ + scol;
    const unsigned short* bSrc1 = bSrc0 + (size_t)128*D_;   // same swz (row+128)
    const int wdst = wave * 512;        // elem offset of wave's DMA dest

    // ---- fragment read offsets (swizzled)
    int aoff[4], boff[4];
    #pragma unroll
    for (int fm = 0; fm < 4; ++fm) {
        const int row = wm2*64 + fm*16 + lr;
        aoff[fm] = row*32 + (quad ^ (row & 3) ^ ((row >> 2) & 3))*8;
    }
    #pragma unroll
    for (int fn = 0; fn < 4; ++fn) {
        const int row = wn4*64 + fn*16 + lr;
        boff[fn] = 4096 + row*32 + (quad ^ (row & 3) ^ ((row >> 2) & 3))*8;
    }

    f32x4 acc[4][4];
    #pragma unroll
    for (int i = 0; i < 4; ++i)
        #pragma unroll
        for (int j = 0; j < 4; ++j)
            acc[i][j] = (f32x4){0.f, 0.f, 0.f, 0.f};

    // ---- prologue: stage tile 0 only
    gl2lds16(aSrc,  lds +        wdst);
    gl2lds16(bSrc0, lds + 4096 + wdst);
    gl2lds16(bSrc1, lds + 8192 + wdst);
    aSrc += 32; bSrc0 += 32; bSrc1 += 32;
    VMCNT0();
    BARRIER();

    int cur = 0;
    #pragma unroll 1
    for (int t = 0; t < 32; ++t) {
        const unsigned short* Sl = lds + cur*12288;
        unsigned short*       S2 = lds + (cur ^ 1)*12288;
        short8 afr[4], bfr[4];

        // phase 0: all A frags + B frags 0,1; stage A + B0 of tile t+1
        #pragma unroll
        for (int fm = 0; fm < 4; ++fm)
            afr[fm] = *reinterpret_cast<const short8*>(&Sl[aoff[fm]]);
        bfr[0] = *reinterpret_cast<const short8*>(&Sl[boff[0]]);
        bfr[1] = *reinterpret_cast<const short8*>(&Sl[boff[1]]);
        if (t < 31) {
            gl2lds16(aSrc,  S2 +        wdst);
            gl2lds16(bSrc0, S2 + 4096 + wdst);
        }
        __builtin_amdgcn_s_setprio(1);
        #pragma unroll
        for (int fm = 0; fm < 4; ++fm)
            #pragma unroll
            for (int fn = 0; fn < 2; ++fn)
                acc[fm][fn] = __builtin_amdgcn_mfma_f32_16x16x32_bf16(
                    afr[fm], bfr[fn], acc[fm][fn], 0, 0, 0);
        __builtin_amdgcn_s_setprio(0);

        // phase 1: B frags 2,3 (reuse afr); stage B1 of tile t+1
        bfr[2] = *reinterpret_cast<const short8*>(&Sl[boff[2]]);
        bfr[3] = *reinterpret_cast<const short8*>(&Sl[boff[3]]);
        if (t < 31) {
            gl2lds16(bSrc1, S2 + 8192 + wdst);
            aSrc += 32; bSrc0 += 32; bSrc1 += 32;
        }
        __builtin_amdgcn_s_setprio(1);
        #pragma unroll
        for (int fm = 0; fm < 4; ++fm)
            #pragma unroll
            for (int fn = 2; fn < 4; ++fn)
                acc[fm][fn] = __builtin_amdgcn_mfma_f32_16x16x32_bf16(
                    afr[fm], bfr[fn], acc[fm][fn], 0, 0, 0);
        __builtin_amdgcn_s_setprio(0);

        // drain tile t+1's 3 loads (mostly landed under the MFMAs above)
        VMCNT0();
        BARRIER();
        cur ^= 1;
    }

    // ---- epilogue ----
    const int colbase = bn*256 + wn4*64 + lr;         // output col 0..2047
    const int mbase   = bm*128 + wm2*64 + quad*4;     // output row base
    if (bn < 4) {
        // K half: kp[m][n]
        #pragma unroll
        for (int fn = 0; fn < 4; ++fn) {
            const int n = colbase + fn*16;
            const float bb = bias[n];
            #pragma unroll
            for (int fm = 0; fm < 4; ++fm) {
                unsigned short* Cp = kp + (size_t)(mbase + fm*16)*1024 + n;
                #pragma unroll
                for (int r = 0; r < 4; ++r)
                    Cp[(size_t)r * 1024] = f2bf(acc[fm][fn][r] + bb);
            }
        }
    } else {
        // V half transposed: vt[b*1024 + d][key]
        const int b = bm >> 5;                        // 32 bm-tiles per batch
        const int key0 = mbase - b*4096;
        #pragma unroll
        for (int fn = 0; fn < 4; ++fn) {
            const int n = colbase + fn*16;
            const float bb = bias[n];
            unsigned short* vrow = vt + (size_t)(b*1024 + n - 1024) * HW_;
            #pragma unroll
            for (int fm = 0; fm < 4; ++fm) {
                ushort4 o;
                o.x = f2bf(acc[fm][fn][0] + bb);
                o.y = f2bf(acc[fm][fn][1] + bb);
                o.z = f2bf(acc[fm][fn][2] + bb);
                o.w = f2bf(acc[fm][fn][3] + bb);
                *reinterpret_cast<ushort4*>(vrow + key0 + fm*16) = o;
            }
        }
    }
}

// ---------------------------------------------------------------------------
// Split-K MFMA GEMM for skinny M: P[sk][m][n] = A[m, skKS:(sk+1)KS] @ W^T.
// (standalone; used for the output projection)
// ---------------------------------------------------------------------------
__global__ __launch_bounds__(256) void gemm_splitk_kernel(
    const unsigned short* __restrict__ A, const unsigned short* __restrict__ W,
    float* __restrict__ P, int K, int KS)
{
    __shared__ __align__(16) unsigned short As[2048];
    __shared__ __align__(16) unsigned short Bs[2048];
    const int tid = threadIdx.x;
    const int wave = tid >> 6, lane = tid & 63;
    const int lr = lane & 15, quad = lane >> 4;
    const int bn = blockIdx.x, bm = blockIdx.y, sk = blockIdx.z;

    const int r0 = tid >> 2;
    const int xs = (r0 & 3) ^ ((r0 >> 2) & 3);
    const int kc = (tid & 3) ^ xs;
    const unsigned short* ap = A + (size_t)(bm*64 + r0)*K + sk*KS + kc*8;
    const unsigned short* bp = W + (size_t)(bn*64 + r0)*K + sk*KS + kc*8;
    unsigned short* asd = As + wave*512;
    unsigned short* bsd = Bs + wave*512;

    f32x4 acc[4];
    #pragma unroll
    for (int j = 0; j < 4; ++j) acc[j] = (f32x4){0.f,0.f,0.f,0.f};

    const int arow = wave*16 + lr;
    const int xa = (arow & 3) ^ ((arow >> 2) & 3);
    const int aoff = (arow*4 + (quad ^ xa))*8;
    int boff[4];
    #pragma unroll
    for (int j = 0; j < 4; ++j) {
        const int brow = j*16 + lr;
        const int xb = (brow & 3) ^ ((brow >> 2) & 3);
        boff[j] = (brow*4 + (quad ^ xb))*8;
    }

    const int nsteps = KS >> 5;
    for (int s = 0; s < nsteps; ++s) {
        gl2lds16(ap, asd); gl2lds16(bp, bsd);
        ap += 32; bp += 32;
        __syncthreads();
        const short8 af = *reinterpret_cast<const short8*>(&As[aoff]);
        short8 bf[4];
        #pragma unroll
        for (int j = 0; j < 4; ++j)
            bf[j] = *reinterpret_cast<const short8*>(&Bs[boff[j]]);
        #pragma unroll
        for (int j = 0; j < 4; ++j)
            acc[j] = __builtin_amdgcn_mfma_f32_16x16x32_bf16(af, bf[j], acc[j], 0, 0, 0);
        __syncthreads();
    }

    float* Pb = P + ((size_t)sk*MP_ + bm*64)*1024 + bn*64;
    const int m0 = wave*16 + quad*4;
    #pragma unroll
    for (int j = 0; j < 4; ++j)
        #pragma unroll
        for (int r = 0; r < 4; ++r)
            Pb[(size_t)(m0 + r)*1024 + j*16 + lr] = acc[j][r];
}

// ---------------------------------------------------------------------------
// Reduce split-K partials + bias.
// ---------------------------------------------------------------------------
__global__ __launch_bounds__(256) void reduce_kernel(
    const float* __restrict__ P, const float* __restrict__ bias,
    float* __restrict__ Cout, int SK)
{
    const int i4 = blockIdx.x * 256 + threadIdx.x;
    const int c4 = i4 & 255;
    float4 s = reinterpret_cast<const float4*>(bias)[c4];
    for (int sk = 0; sk < SK; ++sk) {
        const float4 p = reinterpret_cast<const float4*>(P + (size_t)sk*MP_*1024)[i4];
        s.x += p.x; s.y += p.y; s.z += p.z; s.w += p.w;
    }
    reinterpret_cast<float4*>(Cout)[i4] = s;
}

// ---------------------------------------------------------------------------
// MFMA flash attention, fixed-max softmax, split-K partial outputs.
// LDS 48KB STATIC (3 blocks/CU). R11: T14 async-STAGE split — K/V for tile
// kt+1 are global_load'ed into REGISTERS before compute(kt) (~2000 cyc to
// land), then ds_write'd to LDS after the barrier. Occupancy-neutral
// pipelining (R5's dbuf cost a block/CU; this keeps LDS at 48KB).
// kreg/vreg = +32 VGPR; watch for spill (would show as WRITE_SIZE spike).
// XCD-group swizzle (R8): 4 qt siblings sharing a K/V chunk on ONE XCD.
// NCH=2 (R9). p = mask ? exp(s) : 0; mpack guarantees l > 0.
// NOTE: no global atomicAdd accumulation — cross-XCD RMW fanout multiplied
// WRITE_SIZE ~8x and cost +115 us.
// ---------------------------------------------------------------------------
__global__ __launch_bounds__(256) void flash_kernel(
    const float* __restrict__ qp, const unsigned short* __restrict__ kp,
    const unsigned short* __restrict__ vt, const unsigned int* __restrict__ mpack,
    float* __restrict__ partO, float* __restrict__ partL)
{
    __shared__ __align__(16) unsigned char smem[49152];
    unsigned short* Ks  = (unsigned short*)smem;            // 16 KB
    unsigned short* Vts = (unsigned short*)(smem + 16384);  // 16 KB
    unsigned short* Qs  = (unsigned short*)(smem + 32768);  // 4608 B
    unsigned short* Ps  = (unsigned short*)(smem + 37376);  // 10240 B
    unsigned int*   MWs = (unsigned int*)  (smem + 47616);  // 512 B
    float*          mlW = (float*)         (smem + 48128);  // 512 B
    float*          Om  = (float*)smem;                     // merge alias

    const int tid = threadIdx.x;
    const int wave = tid >> 6, lane = tid & 63;
    const int lr = lane & 15, quad = lane >> 4;

    // XCD-group swizzle: XCD (bid&7) owns CPX consecutive orig ids; qt in
    // the LOW bits of orig keeps the 4 K/V-sharing siblings on one XCD.
    const int CPX  = (4*H_*B_*NCH_) / 8;         // blocks per XCD
    const int bid  = blockIdx.x;                 // 1D grid
    const int orig = (bid & 7) * CPX + (bid >> 3);
    const int qt   = orig & 3;
    const int rest = orig >> 2;
    const int h    = rest % H_;
    const int zz   = rest / H_;                  // 0..(B_*NCH_-1)
    const int b    = zz / NCH_, ks = zz % NCH_;
    const int kb0 = ks * KCH_;

    {   // stage Q (scaled by 1/sqrt(64) -- exact pow2, folded into bf16)
        const int q = tid >> 3, dc = (tid & 7) * 8;
        const int qg = qt*QT_ + q;
        float4 v0 = make_float4(0.f,0.f,0.f,0.f), v1 = v0;
        if (qg < NQ_) {
            const float* src = qp + ((size_t)(b*NQ_ + qg))*D_ + h*HD_ + dc;
            v0 = *reinterpret_cast<const float4*>(src);
            v1 = *reinterpret_cast<const float4*>(src + 4);
        }
        ushort8v o;
        o[0]=f2bf(v0.x*0.125f); o[1]=f2bf(v0.y*0.125f);
        o[2]=f2bf(v0.z*0.125f); o[3]=f2bf(v0.w*0.125f);
        o[4]=f2bf(v1.x*0.125f); o[5]=f2bf(v1.y*0.125f);
        o[6]=f2bf(v1.z*0.125f); o[7]=f2bf(v1.w*0.125f);
        *reinterpret_cast<ushort8v*>(&Qs[q*72 + dc]) = o;
    }

    const unsigned short* kptr[4];
    const unsigned short* vptr[4];
    #pragma unroll
    for (int i = 0; i < 4; ++i) {
        const int s = i*256 + tid;
        const int key = s >> 3, jg = (s & 7) ^ (key & 7);
        kptr[i] = kp + ((size_t)(b*HW_) + kb0 + key)*1024 + h*HD_ + jg*8;
        const int d = s >> 4, js = s & 15, jg2 = js ^ (d & 15);
        vptr[i] = vt + ((size_t)(b*1024 + h*HD_ + d))*HW_ + kb0 + jg2*8;
    }

    int koff[2][2], voff[4];
    #pragma unroll
    for (int kj = 0; kj < 2; ++kj)
        #pragma unroll
        for (int ds = 0; ds < 2; ++ds) {
            const int key_l = wave*32 + kj*16 + lr;
            const int jg = ds*4 + quad;
            koff[kj][ds] = (key_l*8 + (jg ^ (key_l & 7))) * 8;
        }
    #pragma unroll
    for (int dj = 0; dj < 4; ++dj) {
        const int d_l = dj*16 + lr;
        const int jg = wave*4 + quad;
        voff[dj] = (d_l*16 + (jg ^ (d_l & 15))) * 8;
    }

    float lreg[8];
    #pragma unroll
    for (int i = 0; i < 8; ++i) lreg[i] = 0.f;
    f32x4 Ov[2][4];
    #pragma unroll
    for (int i = 0; i < 2; ++i)
        #pragma unroll
        for (int j = 0; j < 4; ++j)
            Ov[i][j] = (f32x4){0.f,0.f,0.f,0.f};

    // ---- T14 register staging: global -> reg (issue early), reg -> LDS late
    ushort8v kreg[4], vreg[4];
    unsigned int mreg = 0;
    #define LOADREG(kt_)                                                      \
        do {                                                                  \
            _Pragma("unroll")                                                 \
            for (int i = 0; i < 4; ++i) {                                     \
                kreg[i] = *reinterpret_cast<const ushort8v*>(kptr[i]);        \
                vreg[i] = *reinterpret_cast<const ushort8v*>(vptr[i]);        \
                kptr[i] += 128*1024; vptr[i] += 128;                          \
            }                                                                 \
            if (tid < 128)                                                    \
                mreg = mpack[((size_t)(b*128 + qt*QT_ + (tid & 31)))*128 +    \
                             (ks*(KCH_/32) + (kt_)*4 + (tid >> 5))];          \
        } while (0)

    LOADREG(0);

    #pragma unroll 1
    for (int kt = 0; kt < NT_; ++kt) {
        __syncthreads();    // everyone done READING LDS from tile kt-1
        #pragma unroll
        for (int i = 0; i < 4; ++i) {
            *reinterpret_cast<ushort8v*>(Ks  + (i*256 + tid)*8) = kreg[i];
            *reinterpret_cast<ushort8v*>(Vts + (i*256 + tid)*8) = vreg[i];
        }
        if (tid < 128) MWs[(tid >> 5)*32 + (tid & 31)] = mreg;
        if (kt + 1 < NT_) LOADREG(kt + 1);   // in flight during compute below
        __syncthreads();    // LDS writes visible block-wide

        // ---- QK^T ----
        f32x4 S[2][2];
        #pragma unroll
        for (int i = 0; i < 2; ++i)
            #pragma unroll
            for (int kj = 0; kj < 2; ++kj)
                S[i][kj] = (f32x4){0.f,0.f,0.f,0.f};
        #pragma unroll
        for (int ds = 0; ds < 2; ++ds) {
            short8 aq[2], bk[2];
            aq[0] = *reinterpret_cast<const short8*>(&Qs[(     lr)*72 + ds*32 + quad*8]);
            aq[1] = *reinterpret_cast<const short8*>(&Qs[(16 + lr)*72 + ds*32 + quad*8]);
            bk[0] = *reinterpret_cast<const short8*>(&Ks[koff[0][ds]]);
            bk[1] = *reinterpret_cast<const short8*>(&Ks[koff[1][ds]]);
            #pragma unroll
            for (int i = 0; i < 2; ++i)
                #pragma unroll
                for (int kj = 0; kj < 2; ++kj)
                    S[i][kj] = __builtin_amdgcn_mfma_f32_16x16x32_bf16(
                        aq[i], bk[kj], S[i][kj], 0, 0, 0);
        }

        // ---- p = mask ? exp(s) : 0; per-lane l; P write (bf16, transposed) --
        #pragma unroll
        for (int i = 0; i < 2; ++i) {
            #pragma unroll
            for (int r = 0; r < 4; ++r) {
                const int q = i*16 + quad*4 + r;
                const unsigned int mw = MWs[wave*32 + q];
                const float p0 = ((mw >> lr) & 1u)        ? __expf(S[i][0][r]) : 0.f;
                const float p1 = ((mw >> (16 + lr)) & 1u) ? __expf(S[i][1][r]) : 0.f;
                lreg[i*4+r] += p0 + p1;
                const float p0n = __shfl_xor(p0, 1);
                const float p1n = __shfl_xor(p1, 1);
                if (!(lr & 1)) {
                    const unsigned int w0 = (unsigned)f2bf(p0) | ((unsigned)f2bf(p0n) << 16);
                    const unsigned int w1 = (unsigned)f2bf(p1) | ((unsigned)f2bf(p1n) << 16);
                    *reinterpret_cast<unsigned int*>(&Ps[wave*1280 + q*40 + lr])      = w0;
                    *reinterpret_cast<unsigned int*>(&Ps[wave*1280 + q*40 + 16 + lr]) = w1;
                }
            }
        }

        // ---- P @ V accumulate ----
        short8 pf[2], vf[4];
        #pragma unroll
        for (int i = 0; i < 2; ++i)
            pf[i] = *reinterpret_cast<const short8*>(&Ps[wave*1280 + (i*16+lr)*40 + quad*8]);
        #pragma unroll
        for (int dj = 0; dj < 4; ++dj)
            vf[dj] = *reinterpret_cast<const short8*>(&Vts[voff[dj]]);
        #pragma unroll
        for (int i = 0; i < 2; ++i)
            #pragma unroll
            for (int dj = 0; dj < 4; ++dj)
                Ov[i][dj] = __builtin_amdgcn_mfma_f32_16x16x32_bf16(
                    pf[i], vf[dj], Ov[i][dj], 0, 0, 0);
    }
    #undef LOADREG

    // ---- block merge (4 waves) then partial store ----
    __syncthreads();
    #pragma unroll
    for (int i = 0; i < 2; ++i)
        #pragma unroll
        for (int r = 0; r < 4; ++r) {
            float l = lreg[i*4+r];
            #pragma unroll
            for (int o = 1; o < 16; o <<= 1) l += __shfl_xor(l, o);
            if (lr == 0) mlW[wave*32 + i*16 + quad*4 + r] = l;
        }
    #pragma unroll
    for (int i = 0; i < 2; ++i)
        #pragma unroll
        for (int dj = 0; dj < 4; ++dj)
            #pragma unroll
            for (int r = 0; r < 4; ++r) {
                const int q = i*16 + quad*4 + r;
                Om[wave*2112 + q*66 + dj*16 + lr] = Ov[i][dj][r];
            }
    __syncthreads();
    {
        const int q = tid >> 3, dc = (tid & 7) * 8;
        float L = 0.f;
        #pragma unroll
        for (int w = 0; w < 4; ++w) L += mlW[w*32 + q];
        float os[8] = {};
        #pragma unroll
        for (int w = 0; w < 4; ++w)
            #pragma unroll
            for (int j = 0; j < 8; ++j)
                os[j] += Om[w*2112 + q*66 + dc + j];
        const size_t pr = (((size_t)(b*H_ + h))*NCH_ + ks)*128 + qt*QT_ + q;
        *reinterpret_cast<float4*>(&partO[pr*HD_ + dc])     = make_float4(os[0],os[1],os[2],os[3]);
        *reinterpret_cast<float4*>(&partO[pr*HD_ + dc + 4]) = make_float4(os[4],os[5],os[6],os[7]);
        if ((tid & 7) == 0) partL[pr] = L;
    }
}

// ---------------------------------------------------------------------------
// hilo_a + combine FUSED. Per output row (b,qi): sum the NCH_ chunk
// partials, divide by L, hi/lo split -> ctx_cat [hi|lo|hi] row stride 3072.
// Pad rows (>=400) zeroed.
// ---------------------------------------------------------------------------
__global__ __launch_bounds__(256) void hilo_a_kernel(
    const float* __restrict__ partO, const float* __restrict__ partL,
    unsigned short* __restrict__ y)
{
    const int row = blockIdx.x;   // 0..511
    const int tid = threadIdx.x;
    unsigned short* yr = y + (size_t)row * 3072;
    if (row >= B_*NQ_) {
        const ushort4 z = make_ushort4(0,0,0,0);
        reinterpret_cast<ushort4*>(yr)[tid]        = z;
        reinterpret_cast<ushort4*>(yr + 1024)[tid] = z;
        reinterpret_cast<ushort4*>(yr + 2048)[tid] = z;
        return;
    }
    const int b = row / NQ_, qi = row % NQ_;
    const int h = tid >> 4, d4 = (tid & 15) * 4;
    float4 O = make_float4(0.f, 0.f, 0.f, 0.f);
    float L = 0.f;
    #pragma unroll
    for (int i = 0; i < NCH_; ++i) {
        const size_t pr = (((size_t)(b*H_ + h))*NCH_ + i)*128 + qi;
        const float4 p = *reinterpret_cast<const float4*>(partO + pr*HD_ + d4);
        O.x += p.x; O.y += p.y; O.z += p.z; O.w += p.w;
        L += partL[pr];
    }
    const float ri = 1.0f / L;
    const float4 v = make_float4(O.x*ri, O.y*ri, O.z*ri, O.w*ri);
    ushort4 hi, lo;
    hi.x = f2bf(v.x); hi.y = f2bf(v.y); hi.z = f2bf(v.z); hi.w = f2bf(v.w);
    lo.x = f2bf(v.x - bf2f(hi.x)); lo.y = f2bf(v.y - bf2f(hi.y));
    lo.z = f2bf(v.z - bf2f(hi.z)); lo.w = f2bf(v.w - bf2f(hi.w));
    reinterpret_cast<ushort4*>(yr)[tid]        = hi;
    reinterpret_cast<ushort4*>(yr + 1024)[tid] = lo;
    reinterpret_cast<ushort4*>(yr + 2048)[tid] = hi;
}

// ---------------------------------------------------------------------------
// Workspace (bytes):
//   qp       @ 0           (1,638,400)
//   mpack    @ 1,638,400   (262,144)
//   wfull_bf @ 1,900,544   (6,291,456)
//   qn_bf    @ 8,192,000   (1,048,576)
//   ctx_cat  @ 9,240,576   (3,145,728)
//   wout_cat @ 12,386,304  (6,291,456)
//   P        @ 18,677,760  (16,777,216)
//   partL    @ 37,093,376  (262,144)
//   partO    @ 37,355,520  (16,777,216)
//   kvn_bf   @ 54,132,736  (33,554,432)
//   kp       @ 87,687,168  (33,554,432)  bf16 [16384][1024]
//   vt       @ 121,241,600 (33,554,432)  bf16 [4096][4096]  -> ~154.8 MB
// ---------------------------------------------------------------------------
extern "C" void kernel_launch(void* const* d_in, const int* in_sizes, int n_in,
                              void* d_out, int out_size, void* d_ws, size_t ws_size,
                              hipStream_t stream)
{
    const float* q     = (const float*)d_in[0];
    const float* kv    = (const float*)d_in[1];
    const int*   mask  = (const int*)  d_in[2];
    const float* in_w  = (const float*)d_in[3];
    const float* in_b  = (const float*)d_in[4];
    const float* out_w = (const float*)d_in[5];
    const float* out_b = (const float*)d_in[6];
    const float* g_q   = (const float*)d_in[7];
    const float* b_q   = (const float*)d_in[8];
    const float* g_kv  = (const float*)d_in[9];
    const float* b_kv  = (const float*)d_in[10];
    float* out = (float*)d_out;

    char* ws = (char*)d_ws;
    float*          qp       = (float*)         (ws + 0);
    unsigned int*   mpackp   = (unsigned int*)  (ws + 1638400);
    unsigned short* wfull_bf = (unsigned short*)(ws + 1900544);
    unsigned short* qn_bf    = (unsigned short*)(ws + 8192000);
    unsigned short* ctx_cat  = (unsigned short*)(ws + 9240576);
    unsigned short* wout_cat = (unsigned short*)(ws + 12386304);
    float*          P        = (float*)         (ws + 18677760);
    float*          partL    = (float*)         (ws + 37093376);
    float*          partO    = (float*)         (ws + 37355520);
    unsigned short* kvn_bf   = (unsigned short*)(ws + 54132736);
    unsigned short* kp       = (unsigned short*)(ws + 87687168);
    unsigned short* vt       = (unsigned short*)(ws + 121241600);

    // 48 KiB dynamic LDS for the fused gemm_kv (3 blocks/CU: 144 <= 160 KiB).
    static bool attr_set = false;
    if (!attr_set) {
        hipFuncSetAttribute(reinterpret_cast<const void*>(gemm_kv_kernel),
                            hipFuncAttributeMaxDynamicSharedMemorySize, 49152);
        attr_set = true;
    }

    // --- prep (fused: ln_kv | wconv | ln_q) ---
    prep_kernel<<<7296, 256, 0, stream>>>(
        kv, g_kv, b_kv, kvn_bf,
        q,  g_q,  b_q,  qn_bf,
        in_w, wfull_bf);

    // --- FUSED: K|V proj [0,1024) + Q-proj [1024,2048) + hilo_w [2048,3072)
    //     + mpack [3072,3584) ---
    gemm_kv_kernel<<<dim3(3584), 512, 49152, stream>>>(
        kvn_bf, wfull_bf + (size_t)D_*D_, in_b + D_, kp, vt,
        qn_bf, wfull_bf, P,
        out_w, wout_cat, mask, mpackp);
    reduce_kernel<<<B_*NQ_*D_/4/256, 256, 0, stream>>>(P, in_b, qp, 8);

    // --- MFMA flash attention (XCD-grouped, NCH=2, T14 reg-staged) ---
    flash_kernel<<<dim3(4*H_*B_*NCH_), 256, 0, stream>>>(
        qp, kp, vt, mpackp, partO, partL);

    // --- Output projection: fused combine+hi/lo, then split-K MFMA ---
    hilo_a_kernel<<<MP_, 256, 0, stream>>>(partO, partL, ctx_cat);
    gemm_splitk_kernel<<<dim3(D_/64, MP_/64, 8), 256, 0, stream>>>(
        ctx_cat, wout_cat, P, 3*D_, 384);
    reduce_kernel<<<B_*NQ_*D_/4/256, 256, 0, stream>>>(P, out_b, out, 8);
}

// Round 12
// 275.588 us; speedup vs baseline: 1.0108x; 1.0108x over previous
//
#include <hip/hip_runtime.h>
#include <math.h>
#include <stdint.h>

#define B_    4
#define NQ_   100
#define HW_   4096
#define D_    1024
#define H_    16
#define HD_   64
#define NCH_  2          // key chunks per (b,h) for split-K flash
#define KCH_  (HW_/NCH_) // 2048 keys per chunk
#define NT_   (KCH_/128) // 16 K-tiles per flash block
#define QT_   32         // queries per tile (4 tiles cover 100, padded)
#define MP_   512        // padded M for small GEMMs (400 -> 512)

typedef __attribute__((ext_vector_type(8))) short short8;
typedef __attribute__((ext_vector_type(8))) unsigned short ushort8v;
typedef __attribute__((ext_vector_type(4))) float f32x4;

// fp32 -> bf16 RNE
__device__ __forceinline__ unsigned short f2bf(float f) {
    unsigned int u = __float_as_uint(f);
    u += 0x7fffu + ((u >> 16) & 1u);
    return (unsigned short)(u >> 16);
}
__device__ __forceinline__ float bf2f(unsigned short h) {
    return __uint_as_float(((unsigned int)h) << 16);
}

// async global->LDS 16B (LDS ptr is wave-uniform base; HW adds lane*16B)
__device__ __forceinline__ void gl2lds16(const void* g, void* l) {
    typedef __attribute__((address_space(1))) unsigned int gu32;
    typedef __attribute__((address_space(3))) unsigned int lu32;
    __builtin_amdgcn_global_load_lds(
        reinterpret_cast<gu32*>(reinterpret_cast<uintptr_t>(g)),
        reinterpret_cast<lu32*>(reinterpret_cast<uintptr_t>(l)),
        16, 0, 0);
}

#define VMCNT0() asm volatile("s_waitcnt vmcnt(0)" ::: "memory")
#define BARRIER() do { __builtin_amdgcn_s_barrier(); \
                       __builtin_amdgcn_sched_barrier(0); } while (0)

// ---------------------------------------------------------------------------
// LayerNorm + bf16 helper: one wave handles one row. Rows >= real_rows
// write zeros (padding).
// ---------------------------------------------------------------------------
__device__ __forceinline__ void ln_row(
    const float* __restrict__ x, const float* __restrict__ g,
    const float* __restrict__ be, unsigned short* __restrict__ y,
    int row, int real_rows, int lane)
{
    unsigned short* yr = y + (size_t)row * D_;
    if (row >= real_rows) {
        #pragma unroll
        for (int k = 0; k < 4; ++k)
            *reinterpret_cast<ushort4*>(yr + lane*4 + k*256) = make_ushort4(0,0,0,0);
        return;
    }
    const float* xr = x + (size_t)row * D_;
    float4 v[4];
    float s = 0.f, ss = 0.f;
    #pragma unroll
    for (int k = 0; k < 4; ++k) {
        v[k] = *reinterpret_cast<const float4*>(xr + lane*4 + k*256);
        s  += v[k].x + v[k].y + v[k].z + v[k].w;
        ss += v[k].x*v[k].x + v[k].y*v[k].y + v[k].z*v[k].z + v[k].w*v[k].w;
    }
    #pragma unroll
    for (int o = 1; o < 64; o <<= 1) {
        s  += __shfl_xor(s,  o);
        ss += __shfl_xor(ss, o);
    }
    const float mu = s * (1.0f / D_);
    const float rs = rsqrtf(ss * (1.0f / D_) - mu*mu + 1e-5f);
    #pragma unroll
    for (int k = 0; k < 4; ++k) {
        const float4 gg = *reinterpret_cast<const float4*>(g  + lane*4 + k*256);
        const float4 bb = *reinterpret_cast<const float4*>(be + lane*4 + k*256);
        ushort4 o;
        o.x = f2bf((v[k].x - mu) * rs * gg.x + bb.x);
        o.y = f2bf((v[k].y - mu) * rs * gg.y + bb.y);
        o.z = f2bf((v[k].z - mu) * rs * gg.z + bb.z);
        o.w = f2bf((v[k].w - mu) * rs * gg.w + bb.w);
        *reinterpret_cast<ushort4*>(yr + lane*4 + k*256) = o;
    }
}

// ---------------------------------------------------------------------------
// Prep mega-kernel (R12: back to the R10 split — hilo_w/mpack live HERE;
// R11 showed moving them into the GEMM launch steals BW from gemm_kv at a
// net loss. Backfill fusion pays only for compute-light launch-bound work.)
//   [0,    4096): ln_kv   (4 rows/block, 16384 rows)
//   [4096, 7168): wconv   in_w -> wfull_bf (float4/thread)
//   [7168, 8192): hilo_w  out_w -> [hi|hi|lo], row stride 3072
//   [8192, 8704): mpack   mask bits; all-masked row -> all-ones
//   [8704, 8832): ln_q    (4 rows/block, 400 real of 512)
// ---------------------------------------------------------------------------
__global__ __launch_bounds__(256) void prep_kernel(
    const float* __restrict__ kv,   const float* __restrict__ g_kv,
    const float* __restrict__ b_kv, unsigned short* __restrict__ kvn,
    const float* __restrict__ qf,   const float* __restrict__ g_q,
    const float* __restrict__ b_q,  unsigned short* __restrict__ qn,
    const float* __restrict__ in_w, unsigned short* __restrict__ wfull,
    const float* __restrict__ out_w, unsigned short* __restrict__ wout,
    const int* __restrict__ mask,   unsigned int* __restrict__ mp)
{
    __shared__ int red[4];
    const int bid = blockIdx.x, tid = threadIdx.x;

    if (bid < 4096) {                       // ---- ln_kv
        ln_row(kv, g_kv, b_kv, kvn, bid*4 + (tid >> 6), B_*HW_, tid & 63);
    } else if (bid < 7168) {                // ---- wconv
        const int i = (bid - 4096)*256 + tid;
        const float4 v = reinterpret_cast<const float4*>(in_w)[i];
        ushort4 o;
        o.x = f2bf(v.x); o.y = f2bf(v.y); o.z = f2bf(v.z); o.w = f2bf(v.w);
        reinterpret_cast<ushort4*>(wfull)[i] = o;
    } else if (bid < 8192) {                // ---- hilo_w
        const int row = bid - 7168;         // 0..1023
        const float4 v = reinterpret_cast<const float4*>(out_w + (size_t)row * D_)[tid];
        ushort4 hi, lo;
        hi.x = f2bf(v.x); hi.y = f2bf(v.y); hi.z = f2bf(v.z); hi.w = f2bf(v.w);
        lo.x = f2bf(v.x - bf2f(hi.x)); lo.y = f2bf(v.y - bf2f(hi.y));
        lo.z = f2bf(v.z - bf2f(hi.z)); lo.w = f2bf(v.w - bf2f(hi.w));
        unsigned short* yr = wout + (size_t)row * 3072;
        reinterpret_cast<ushort4*>(yr)[tid]        = hi;
        reinterpret_cast<ushort4*>(yr + 1024)[tid] = hi;
        reinterpret_cast<ushort4*>(yr + 2048)[tid] = lo;
    } else if (bid < 8704) {                // ---- mpack
        const int mblk = bid - 8192;        // 0..511
        const int qrow = mblk & 127, mb = mblk >> 7;
        unsigned int word = 0;
        if (qrow < NQ_ && tid < 128) {
            const int4* mr = reinterpret_cast<const int4*>(
                mask + ((size_t)(mb*NQ_ + qrow))*HW_ + tid*32);
            #pragma unroll
            for (int j = 0; j < 8; ++j) {
                const int4 v = mr[j];
                word |= (v.x!=0 ? 1u:0u) << (4*j);
                word |= (v.y!=0 ? 1u:0u) << (4*j+1);
                word |= (v.z!=0 ? 1u:0u) << (4*j+2);
                word |= (v.w!=0 ? 1u:0u) << (4*j+3);
            }
        }
        const int wany = __any(word != 0) ? 1 : 0;
        if ((tid & 63) == 0) red[tid >> 6] = wany;
        __syncthreads();
        const int hasany = red[0] | red[1] | red[2] | red[3];
        if (tid < 128)
            mp[((size_t)(mb*128 + qrow))*128 + tid] = hasany ? word : 0xFFFFFFFFu;
    } else {                                // ---- ln_q
        ln_row(qf, g_q, b_q, qn, (bid - 8704)*4 + (tid >> 6), B_*NQ_, tid & 63);
    }
}

// ---------------------------------------------------------------------------
// FUSED (R10 config): gemm_kv (blocks [0,1024), FROZEN R7 body) + Q-proj
// split-K GEMM (blocks [1024,2048), threads 0-255, K=1024/KS=128).
// Light latency-bound Q-proj blocks backfill CU slots while gemm_kv idles
// at barriers (R10: absorbed ~12us for +2us). R11 lesson: do NOT add
// bandwidth-heavy blocks (hilo_w/mpack) here — they steal BW at a net loss.
// WATCH: VGPR must stay <=64 for the gemm path (R6 spill lesson).
// gemm_kv: BM=128 x BN=256, BK=32, wave tile 64x64, ring-2 dbuf, 1 barrier
// per K-tile, XCD swizzle on bid&7; epilogue bn<4 -> kp, bn>=4 -> vt^T.
// ---------------------------------------------------------------------------
__global__ __launch_bounds__(512, 4) void gemm_kv_kernel(
    const unsigned short* __restrict__ A, const unsigned short* __restrict__ Wb,
    const float* __restrict__ bias, unsigned short* __restrict__ kp,
    unsigned short* __restrict__ vt,
    const unsigned short* __restrict__ qA, const unsigned short* __restrict__ qW,
    float* __restrict__ P)
{
    extern __shared__ __align__(16) unsigned short lds[];

    const int tid  = threadIdx.x;       // 0..511
    const int wave = tid >> 6;          // 0..7
    const int lane = tid & 63;
    const int lr   = lane & 15, quad = lane >> 4;

    if (blockIdx.x >= 1024) {
        // ================= Q-proj split-K path =================
        const int bid2 = blockIdx.x - 1024;         // 0..1023
        const int bn = bid2 & 15, bm = (bid2 >> 4) & 7, sk = bid2 >> 7;
        unsigned short* As = lds;                    // 2048 elems
        unsigned short* Bs = lds + 2048;             // 2048 elems

        const int r0 = (tid & 255) >> 2;
        const int xs = (r0 & 3) ^ ((r0 >> 2) & 3);
        const int kc = (tid & 3) ^ xs;
        const unsigned short* ap = qA + (size_t)(bm*64 + r0)*1024 + sk*128 + kc*8;
        const unsigned short* bp = qW + (size_t)(bn*64 + r0)*1024 + sk*128 + kc*8;
        unsigned short* asd = As + (wave & 3)*512;
        unsigned short* bsd = Bs + (wave & 3)*512;

        f32x4 acc[4];
        #pragma unroll
        for (int j = 0; j < 4; ++j) acc[j] = (f32x4){0.f,0.f,0.f,0.f};

        const int arow = (wave & 3)*16 + lr;
        const int xa = (arow & 3) ^ ((arow >> 2) & 3);
        const int aoff = (arow*4 + (quad ^ xa))*8;
        int boff[4];
        #pragma unroll
        for (int j = 0; j < 4; ++j) {
            const int brow = j*16 + lr;
            const int xb = (brow & 3) ^ ((brow >> 2) & 3);
            boff[j] = (brow*4 + (quad ^ xb))*8;
        }

        #pragma unroll 1
        for (int s = 0; s < 4; ++s) {
            if (tid < 256) { gl2lds16(ap, asd); gl2lds16(bp, bsd); }
            ap += 32; bp += 32;
            __syncthreads();
            if (tid < 256) {
                const short8 af = *reinterpret_cast<const short8*>(&As[aoff]);
                short8 bf[4];
                #pragma unroll
                for (int j = 0; j < 4; ++j)
                    bf[j] = *reinterpret_cast<const short8*>(&Bs[boff[j]]);
                #pragma unroll
                for (int j = 0; j < 4; ++j)
                    acc[j] = __builtin_amdgcn_mfma_f32_16x16x32_bf16(af, bf[j], acc[j], 0, 0, 0);
            }
            __syncthreads();
        }

        if (tid < 256) {
            float* Pb = P + ((size_t)sk*MP_ + bm*64)*1024 + bn*64;
            const int m0 = (wave & 3)*16 + quad*4;
            #pragma unroll
            for (int j = 0; j < 4; ++j)
                #pragma unroll
                for (int r = 0; r < 4; ++r)
                    Pb[(size_t)(m0 + r)*1024 + j*16 + lr] = acc[j][r];
        }
        return;
    }

    // ================= gemm_kv path (FROZEN R7 body) =================
    const int wm2  = wave >> 2;         // 0..1  (M half: 64 rows)
    const int wn4  = wave & 3;          // 0..3  (N quarter: 64 cols)

    // XCD-range swizzle (bijective; 1024 blocks, 8 XCDs)
    const int x  = blockIdx.x & 7;
    const int g  = blockIdx.x >> 3;
    const int bm = x*16 + (g >> 3);     // 0..127  M tile (128 rows)
    const int bn = g & 7;               // 0..7    N tile (256 cols)

    // ---- staging source (pre-swizzled so linear LDS dest ends up swizzled)
    const int srow = tid >> 2;                           // 0..127
    const int sswz = (srow & 3) ^ ((srow >> 2) & 3);
    const int scol = ((tid & 3) ^ sswz) * 8;
    const unsigned short* aSrc  = A  + (size_t)(bm*128 + srow)*D_ + scol;
    const unsigned short* bSrc0 = Wb + (size_t)(bn*256 + srow)*D_ + scol;
    const unsigned short* bSrc1 = bSrc0 + (size_t)128*D_;   // same swz (row+128)
    const int wdst = wave * 512;        // elem offset of wave's DMA dest

    // ---- fragment read offsets (swizzled)
    int aoff[4], boff[4];
    #pragma unroll
    for (int fm = 0; fm < 4; ++fm) {
        const int row = wm2*64 + fm*16 + lr;
        aoff[fm] = row*32 + (quad ^ (row & 3) ^ ((row >> 2) & 3))*8;
    }
    #pragma unroll
    for (int fn = 0; fn < 4; ++fn) {
        const int row = wn4*64 + fn*16 + lr;
        boff[fn] = 4096 + row*32 + (quad ^ (row & 3) ^ ((row >> 2) & 3))*8;
    }

    f32x4 acc[4][4];
    #pragma unroll
    for (int i = 0; i < 4; ++i)
        #pragma unroll
        for (int j = 0; j < 4; ++j)
            acc[i][j] = (f32x4){0.f, 0.f, 0.f, 0.f};

    // ---- prologue: stage tile 0 only
    gl2lds16(aSrc,  lds +        wdst);
    gl2lds16(bSrc0, lds + 4096 + wdst);
    gl2lds16(bSrc1, lds + 8192 + wdst);
    aSrc += 32; bSrc0 += 32; bSrc1 += 32;
    VMCNT0();
    BARRIER();

    int cur = 0;
    #pragma unroll 1
    for (int t = 0; t < 32; ++t) {
        const unsigned short* Sl = lds + cur*12288;
        unsigned short*       S2 = lds + (cur ^ 1)*12288;
        short8 afr[4], bfr[4];

        // phase 0: all A frags + B frags 0,1; stage A + B0 of tile t+1
        #pragma unroll
        for (int fm = 0; fm < 4; ++fm)
            afr[fm] = *reinterpret_cast<const short8*>(&Sl[aoff[fm]]);
        bfr[0] = *reinterpret_cast<const short8*>(&Sl[boff[0]]);
        bfr[1] = *reinterpret_cast<const short8*>(&Sl[boff[1]]);
        if (t < 31) {
            gl2lds16(aSrc,  S2 +        wdst);
            gl2lds16(bSrc0, S2 + 4096 + wdst);
        }
        __builtin_amdgcn_s_setprio(1);
        #pragma unroll
        for (int fm = 0; fm < 4; ++fm)
            #pragma unroll
            for (int fn = 0; fn < 2; ++fn)
                acc[fm][fn] = __builtin_amdgcn_mfma_f32_16x16x32_bf16(
                    afr[fm], bfr[fn], acc[fm][fn], 0, 0, 0);
        __builtin_amdgcn_s_setprio(0);

        // phase 1: B frags 2,3 (reuse afr); stage B1 of tile t+1
        bfr[2] = *reinterpret_cast<const short8*>(&Sl[boff[2]]);
        bfr[3] = *reinterpret_cast<const short8*>(&Sl[boff[3]]);
        if (t < 31) {
            gl2lds16(bSrc1, S2 + 8192 + wdst);
            aSrc += 32; bSrc0 += 32; bSrc1 += 32;
        }
        __builtin_amdgcn_s_setprio(1);
        #pragma unroll
        for (int fm = 0; fm < 4; ++fm)
            #pragma unroll
            for (int fn = 2; fn < 4; ++fn)
                acc[fm][fn] = __builtin_amdgcn_mfma_f32_16x16x32_bf16(
                    afr[fm], bfr[fn], acc[fm][fn], 0, 0, 0);
        __builtin_amdgcn_s_setprio(0);

        // drain tile t+1's 3 loads (mostly landed under the MFMAs above)
        VMCNT0();
        BARRIER();
        cur ^= 1;
    }

    // ---- epilogue ----
    const int colbase = bn*256 + wn4*64 + lr;         // output col 0..2047
    const int mbase   = bm*128 + wm2*64 + quad*4;     // output row base
    if (bn < 4) {
        // K half: kp[m][n]
        #pragma unroll
        for (int fn = 0; fn < 4; ++fn) {
            const int n = colbase + fn*16;
            const float bb = bias[n];
            #pragma unroll
            for (int fm = 0; fm < 4; ++fm) {
                unsigned short* Cp = kp + (size_t)(mbase + fm*16)*1024 + n;
                #pragma unroll
                for (int r = 0; r < 4; ++r)
                    Cp[(size_t)r * 1024] = f2bf(acc[fm][fn][r] + bb);
            }
        }
    } else {
        // V half transposed: vt[b*1024 + d][key]
        const int b = bm >> 5;                        // 32 bm-tiles per batch
        const int key0 = mbase - b*4096;
        #pragma unroll
        for (int fn = 0; fn < 4; ++fn) {
            const int n = colbase + fn*16;
            const float bb = bias[n];
            unsigned short* vrow = vt + (size_t)(b*1024 + n - 1024) * HW_;
            #pragma unroll
            for (int fm = 0; fm < 4; ++fm) {
                ushort4 o;
                o.x = f2bf(acc[fm][fn][0] + bb);
                o.y = f2bf(acc[fm][fn][1] + bb);
                o.z = f2bf(acc[fm][fn][2] + bb);
                o.w = f2bf(acc[fm][fn][3] + bb);
                *reinterpret_cast<ushort4*>(vrow + key0 + fm*16) = o;
            }
        }
    }
}

// ---------------------------------------------------------------------------
// Split-K MFMA GEMM for skinny M: P[sk][m][n] = A[m, skKS:(sk+1)KS] @ W^T.
// (standalone; used for the output projection)
// ---------------------------------------------------------------------------
__global__ __launch_bounds__(256) void gemm_splitk_kernel(
    const unsigned short* __restrict__ A, const unsigned short* __restrict__ W,
    float* __restrict__ P, int K, int KS)
{
    __shared__ __align__(16) unsigned short As[2048];
    __shared__ __align__(16) unsigned short Bs[2048];
    const int tid = threadIdx.x;
    const int wave = tid >> 6, lane = tid & 63;
    const int lr = lane & 15, quad = lane >> 4;
    const int bn = blockIdx.x, bm = blockIdx.y, sk = blockIdx.z;

    const int r0 = tid >> 2;
    const int xs = (r0 & 3) ^ ((r0 >> 2) & 3);
    const int kc = (tid & 3) ^ xs;
    const unsigned short* ap = A + (size_t)(bm*64 + r0)*K + sk*KS + kc*8;
    const unsigned short* bp = W + (size_t)(bn*64 + r0)*K + sk*KS + kc*8;
    unsigned short* asd = As + wave*512;
    unsigned short* bsd = Bs + wave*512;

    f32x4 acc[4];
    #pragma unroll
    for (int j = 0; j < 4; ++j) acc[j] = (f32x4){0.f,0.f,0.f,0.f};

    const int arow = wave*16 + lr;
    const int xa = (arow & 3) ^ ((arow >> 2) & 3);
    const int aoff = (arow*4 + (quad ^ xa))*8;
    int boff[4];
    #pragma unroll
    for (int j = 0; j < 4; ++j) {
        const int brow = j*16 + lr;
        const int xb = (brow & 3) ^ ((brow >> 2) & 3);
        boff[j] = (brow*4 + (quad ^ xb))*8;
    }

    const int nsteps = KS >> 5;
    for (int s = 0; s < nsteps; ++s) {
        gl2lds16(ap, asd); gl2lds16(bp, bsd);
        ap += 32; bp += 32;
        __syncthreads();
        const short8 af = *reinterpret_cast<const short8*>(&As[aoff]);
        short8 bf[4];
        #pragma unroll
        for (int j = 0; j < 4; ++j)
            bf[j] = *reinterpret_cast<const short8*>(&Bs[boff[j]]);
        #pragma unroll
        for (int j = 0; j < 4; ++j)
            acc[j] = __builtin_amdgcn_mfma_f32_16x16x32_bf16(af, bf[j], acc[j], 0, 0, 0);
        __syncthreads();
    }

    float* Pb = P + ((size_t)sk*MP_ + bm*64)*1024 + bn*64;
    const int m0 = wave*16 + quad*4;
    #pragma unroll
    for (int j = 0; j < 4; ++j)
        #pragma unroll
        for (int r = 0; r < 4; ++r)
            Pb[(size_t)(m0 + r)*1024 + j*16 + lr] = acc[j][r];
}

// ---------------------------------------------------------------------------
// Reduce split-K partials + bias (final output projection only).
// ---------------------------------------------------------------------------
__global__ __launch_bounds__(256) void reduce_kernel(
    const float* __restrict__ P, const float* __restrict__ bias,
    float* __restrict__ Cout, int SK)
{
    const int i4 = blockIdx.x * 256 + threadIdx.x;
    const int c4 = i4 & 255;
    float4 s = reinterpret_cast<const float4*>(bias)[c4];
    for (int sk = 0; sk < SK; ++sk) {
        const float4 p = reinterpret_cast<const float4*>(P + (size_t)sk*MP_*1024)[i4];
        s.x += p.x; s.y += p.y; s.z += p.z; s.w += p.w;
    }
    reinterpret_cast<float4*>(Cout)[i4] = s;
}

// ---------------------------------------------------------------------------
// MFMA flash attention, fixed-max softmax, split-K partial outputs.
// Single-buffer 48KB STATIC gl2lds (3 blocks/CU). R5 dbuf and R11 T14 both
// ~null: flash is per-block-overhead bound, NOT staging-latency bound.
// XCD-group swizzle (R8): the 4 qt siblings sharing a K/V chunk run on ONE
// XCD -> chunk in that L2 once. NCH=2 (R9).
// R12: reduce_1 FOLDED into Q-staging — reads the 8 split-K partials of P
// directly (+ in_b), same summation order as reduce_kernel (bit-identical),
// killing the reduce launch + qp round-trip. P is read here BEFORE the
// output projection overwrites it.
// p = mask ? exp(s) : 0 (scale folded into Q staging; mpack guarantees
// l > 0). NOTE: no global atomicAdd accumulation — cross-XCD RMW fanout
// multiplied WRITE_SIZE ~8x and cost +115 us.
// ---------------------------------------------------------------------------
__global__ __launch_bounds__(256) void flash_kernel(
    const float* __restrict__ P, const float* __restrict__ in_b,
    const unsigned short* __restrict__ kp,
    const unsigned short* __restrict__ vt, const unsigned int* __restrict__ mpack,
    float* __restrict__ partO, float* __restrict__ partL)
{
    __shared__ __align__(16) unsigned char smem[49152];
    unsigned short* Ks  = (unsigned short*)smem;            // 16 KB
    unsigned short* Vts = (unsigned short*)(smem + 16384);  // 16 KB
    unsigned short* Qs  = (unsigned short*)(smem + 32768);  // 4608 B
    unsigned short* Ps  = (unsigned short*)(smem + 37376);  // 10240 B
    unsigned int*   MWs = (unsigned int*)  (smem + 47616);  // 512 B
    float*          mlW = (float*)         (smem + 48128);  // 512 B
    float*          Om  = (float*)smem;                     // merge alias

    const int tid = threadIdx.x;
    const int wave = tid >> 6, lane = tid & 63;
    const int lr = lane & 15, quad = lane >> 4;

    // XCD-group swizzle: XCD (bid&7) owns CPX consecutive orig ids; qt in
    // the LOW bits of orig keeps the 4 K/V-sharing siblings on one XCD.
    const int CPX  = (4*H_*B_*NCH_) / 8;         // blocks per XCD
    const int bid  = blockIdx.x;                 // 1D grid
    const int orig = (bid & 7) * CPX + (bid >> 3);
    const int qt   = orig & 3;
    const int rest = orig >> 2;
    const int h    = rest % H_;
    const int zz   = rest / H_;                  // 0..(B_*NCH_-1)
    const int b    = zz / NCH_, ks = zz % NCH_;
    const int kb0 = ks * KCH_;

    {   // stage Q: sum split-K partials + bias (== old reduce), scale 1/8
        const int q = tid >> 3, dc = (tid & 7) * 8;
        const int qg = qt*QT_ + q;
        float4 v0 = make_float4(0.f,0.f,0.f,0.f), v1 = v0;
        if (qg < NQ_) {
            const int row = b*NQ_ + qg;
            const int col = h*HD_ + dc;
            v0 = *reinterpret_cast<const float4*>(in_b + col);
            v1 = *reinterpret_cast<const float4*>(in_b + col + 4);
            #pragma unroll
            for (int sk = 0; sk < 8; ++sk) {
                const float* Pr = P + ((size_t)sk*MP_ + row)*1024 + col;
                const float4 p0 = *reinterpret_cast<const float4*>(Pr);
                const float4 p1 = *reinterpret_cast<const float4*>(Pr + 4);
                v0.x += p0.x; v0.y += p0.y; v0.z += p0.z; v0.w += p0.w;
                v1.x += p1.x; v1.y += p1.y; v1.z += p1.z; v1.w += p1.w;
            }
        }
        ushort8v o;
        o[0]=f2bf(v0.x*0.125f); o[1]=f2bf(v0.y*0.125f);
        o[2]=f2bf(v0.z*0.125f); o[3]=f2bf(v0.w*0.125f);
        o[4]=f2bf(v1.x*0.125f); o[5]=f2bf(v1.y*0.125f);
        o[6]=f2bf(v1.z*0.125f); o[7]=f2bf(v1.w*0.125f);
        *reinterpret_cast<ushort8v*>(&Qs[q*72 + dc]) = o;
    }

    const unsigned short* kptr[4];
    const unsigned short* vptr[4];
    #pragma unroll
    for (int i = 0; i < 4; ++i) {
        const int s = i*256 + tid;
        const int key = s >> 3, jg = (s & 7) ^ (key & 7);
        kptr[i] = kp + ((size_t)(b*HW_) + kb0 + key)*1024 + h*HD_ + jg*8;
        const int d = s >> 4, js = s & 15, jg2 = js ^ (d & 15);
        vptr[i] = vt + ((size_t)(b*1024 + h*HD_ + d))*HW_ + kb0 + jg2*8;
    }

    int koff[2][2], voff[4];
    #pragma unroll
    for (int kj = 0; kj < 2; ++kj)
        #pragma unroll
        for (int ds = 0; ds < 2; ++ds) {
            const int key_l = wave*32 + kj*16 + lr;
            const int jg = ds*4 + quad;
            koff[kj][ds] = (key_l*8 + (jg ^ (key_l & 7))) * 8;
        }
    #pragma unroll
    for (int dj = 0; dj < 4; ++dj) {
        const int d_l = dj*16 + lr;
        const int jg = wave*4 + quad;
        voff[dj] = (d_l*16 + (jg ^ (d_l & 15))) * 8;
    }

    float lreg[8];
    #pragma unroll
    for (int i = 0; i < 8; ++i) lreg[i] = 0.f;
    f32x4 Ov[2][4];
    #pragma unroll
    for (int i = 0; i < 2; ++i)
        #pragma unroll
        for (int j = 0; j < 4; ++j)
            Ov[i][j] = (f32x4){0.f,0.f,0.f,0.f};

    for (int kt = 0; kt < NT_; ++kt) {
        __syncthreads();
        #pragma unroll
        for (int i = 0; i < 4; ++i) {
            gl2lds16(kptr[i], Ks  + (i*256 + wave*64)*8);
            gl2lds16(vptr[i], Vts + (i*256 + wave*64)*8);
            kptr[i] += 128*1024; vptr[i] += 128;
        }
        if (tid < 128) {
            const int mw = tid >> 5, mq = tid & 31;
            MWs[mw*32 + mq] = mpack[((size_t)(b*128 + qt*QT_ + mq))*128 +
                                    (ks*(KCH_/32) + kt*4 + mw)];
        }
        __syncthreads();

        // ---- QK^T ----
        f32x4 S[2][2];
        #pragma unroll
        for (int i = 0; i < 2; ++i)
            #pragma unroll
            for (int kj = 0; kj < 2; ++kj)
                S[i][kj] = (f32x4){0.f,0.f,0.f,0.f};
        #pragma unroll
        for (int ds = 0; ds < 2; ++ds) {
            short8 aq[2], bk[2];
            aq[0] = *reinterpret_cast<const short8*>(&Qs[(     lr)*72 + ds*32 + quad*8]);
            aq[1] = *reinterpret_cast<const short8*>(&Qs[(16 + lr)*72 + ds*32 + quad*8]);
            bk[0] = *reinterpret_cast<const short8*>(&Ks[koff[0][ds]]);
            bk[1] = *reinterpret_cast<const short8*>(&Ks[koff[1][ds]]);
            #pragma unroll
            for (int i = 0; i < 2; ++i)
                #pragma unroll
                for (int kj = 0; kj < 2; ++kj)
                    S[i][kj] = __builtin_amdgcn_mfma_f32_16x16x32_bf16(
                        aq[i], bk[kj], S[i][kj], 0, 0, 0);
        }

        // ---- p = mask ? exp(s) : 0; per-lane l; P write (bf16, transposed) --
        #pragma unroll
        for (int i = 0; i < 2; ++i) {
            #pragma unroll
            for (int r = 0; r < 4; ++r) {
                const int q = i*16 + quad*4 + r;
                const unsigned int mw = MWs[wave*32 + q];
                const float p0 = ((mw >> lr) & 1u)        ? __expf(S[i][0][r]) : 0.f;
                const float p1 = ((mw >> (16 + lr)) & 1u) ? __expf(S[i][1][r]) : 0.f;
                lreg[i*4+r] += p0 + p1;
                const float p0n = __shfl_xor(p0, 1);
                const float p1n = __shfl_xor(p1, 1);
                if (!(lr & 1)) {
                    const unsigned int w0 = (unsigned)f2bf(p0) | ((unsigned)f2bf(p0n) << 16);
                    const unsigned int w1 = (unsigned)f2bf(p1) | ((unsigned)f2bf(p1n) << 16);
                    *reinterpret_cast<unsigned int*>(&Ps[wave*1280 + q*40 + lr])      = w0;
                    *reinterpret_cast<unsigned int*>(&Ps[wave*1280 + q*40 + 16 + lr]) = w1;
                }
            }
        }

        // ---- P @ V accumulate ----
        short8 pf[2], vf[4];
        #pragma unroll
        for (int i = 0; i < 2; ++i)
            pf[i] = *reinterpret_cast<const short8*>(&Ps[wave*1280 + (i*16+lr)*40 + quad*8]);
        #pragma unroll
        for (int dj = 0; dj < 4; ++dj)
            vf[dj] = *reinterpret_cast<const short8*>(&Vts[voff[dj]]);
        #pragma unroll
        for (int i = 0; i < 2; ++i)
            #pragma unroll
            for (int dj = 0; dj < 4; ++dj)
                Ov[i][dj] = __builtin_amdgcn_mfma_f32_16x16x32_bf16(
                    pf[i], vf[dj], Ov[i][dj], 0, 0, 0);
    }

    // ---- block merge (4 waves) then partial store ----
    __syncthreads();
    #pragma unroll
    for (int i = 0; i < 2; ++i)
        #pragma unroll
        for (int r = 0; r < 4; ++r) {
            float l = lreg[i*4+r];
            #pragma unroll
            for (int o = 1; o < 16; o <<= 1) l += __shfl_xor(l, o);
            if (lr == 0) mlW[wave*32 + i*16 + quad*4 + r] = l;
        }
    #pragma unroll
    for (int i = 0; i < 2; ++i)
        #pragma unroll
        for (int dj = 0; dj < 4; ++dj)
            #pragma unroll
            for (int r = 0; r < 4; ++r) {
                const int q = i*16 + quad*4 + r;
                Om[wave*2112 + q*66 + dj*16 + lr] = Ov[i][dj][r];
            }
    __syncthreads();
    {
        const int q = tid >> 3, dc = (tid & 7) * 8;
        float L = 0.f;
        #pragma unroll
        for (int w = 0; w < 4; ++w) L += mlW[w*32 + q];
        float os[8] = {};
        #pragma unroll
        for (int w = 0; w < 4; ++w)
            #pragma unroll
            for (int j = 0; j < 8; ++j)
                os[j] += Om[w*2112 + q*66 + dc + j];
        const size_t pr = (((size_t)(b*H_ + h))*NCH_ + ks)*128 + qt*QT_ + q;
        *reinterpret_cast<float4*>(&partO[pr*HD_ + dc])     = make_float4(os[0],os[1],os[2],os[3]);
        *reinterpret_cast<float4*>(&partO[pr*HD_ + dc + 4]) = make_float4(os[4],os[5],os[6],os[7]);
        if ((tid & 7) == 0) partL[pr] = L;
    }
}

// ---------------------------------------------------------------------------
// hilo_a + combine FUSED. Per output row (b,qi): sum the NCH_ chunk
// partials, divide by L, hi/lo split -> ctx_cat [hi|lo|hi] row stride 3072.
// Pad rows (>=400) zeroed.
// ---------------------------------------------------------------------------
__global__ __launch_bounds__(256) void hilo_a_kernel(
    const float* __restrict__ partO, const float* __restrict__ partL,
    unsigned short* __restrict__ y)
{
    const int row = blockIdx.x;   // 0..511
    const int tid = threadIdx.x;
    unsigned short* yr = y + (size_t)row * 3072;
    if (row >= B_*NQ_) {
        const ushort4 z = make_ushort4(0,0,0,0);
        reinterpret_cast<ushort4*>(yr)[tid]        = z;
        reinterpret_cast<ushort4*>(yr + 1024)[tid] = z;
        reinterpret_cast<ushort4*>(yr + 2048)[tid] = z;
        return;
    }
    const int b = row / NQ_, qi = row % NQ_;
    const int h = tid >> 4, d4 = (tid & 15) * 4;
    float4 O = make_float4(0.f, 0.f, 0.f, 0.f);
    float L = 0.f;
    #pragma unroll
    for (int i = 0; i < NCH_; ++i) {
        const size_t pr = (((size_t)(b*H_ + h))*NCH_ + i)*128 + qi;
        const float4 p = *reinterpret_cast<const float4*>(partO + pr*HD_ + d4);
        O.x += p.x; O.y += p.y; O.z += p.z; O.w += p.w;
        L += partL[pr];
    }
    const float ri = 1.0f / L;
    const float4 v = make_float4(O.x*ri, O.y*ri, O.z*ri, O.w*ri);
    ushort4 hi, lo;
    hi.x = f2bf(v.x); hi.y = f2bf(v.y); hi.z = f2bf(v.z); hi.w = f2bf(v.w);
    lo.x = f2bf(v.x - bf2f(hi.x)); lo.y = f2bf(v.y - bf2f(hi.y));
    lo.z = f2bf(v.z - bf2f(hi.z)); lo.w = f2bf(v.w - bf2f(hi.w));
    reinterpret_cast<ushort4*>(yr)[tid]        = hi;
    reinterpret_cast<ushort4*>(yr + 1024)[tid] = lo;
    reinterpret_cast<ushort4*>(yr + 2048)[tid] = hi;
}

// ---------------------------------------------------------------------------
// Workspace (bytes):
//   qp       @ 0           (1,638,400)   (unused since R12)
//   mpack    @ 1,638,400   (262,144)
//   wfull_bf @ 1,900,544   (6,291,456)
//   qn_bf    @ 8,192,000   (1,048,576)
//   ctx_cat  @ 9,240,576   (3,145,728)
//   wout_cat @ 12,386,304  (6,291,456)
//   P        @ 18,677,760  (16,777,216)
//   partL    @ 37,093,376  (262,144)
//   partO    @ 37,355,520  (16,777,216)
//   kvn_bf   @ 54,132,736  (33,554,432)
//   kp       @ 87,687,168  (33,554,432)  bf16 [16384][1024]
//   vt       @ 121,241,600 (33,554,432)  bf16 [4096][4096]  -> ~154.8 MB
// ---------------------------------------------------------------------------
extern "C" void kernel_launch(void* const* d_in, const int* in_sizes, int n_in,
                              void* d_out, int out_size, void* d_ws, size_t ws_size,
                              hipStream_t stream)
{
    const float* q     = (const float*)d_in[0];
    const float* kv    = (const float*)d_in[1];
    const int*   mask  = (const int*)  d_in[2];
    const float* in_w  = (const float*)d_in[3];
    const float* in_b  = (const float*)d_in[4];
    const float* out_w = (const float*)d_in[5];
    const float* out_b = (const float*)d_in[6];
    const float* g_q   = (const float*)d_in[7];
    const float* b_q   = (const float*)d_in[8];
    const float* g_kv  = (const float*)d_in[9];
    const float* b_kv  = (const float*)d_in[10];
    float* out = (float*)d_out;

    char* ws = (char*)d_ws;
    unsigned int*   mpackp   = (unsigned int*)  (ws + 1638400);
    unsigned short* wfull_bf = (unsigned short*)(ws + 1900544);
    unsigned short* qn_bf    = (unsigned short*)(ws + 8192000);
    unsigned short* ctx_cat  = (unsigned short*)(ws + 9240576);
    unsigned short* wout_cat = (unsigned short*)(ws + 12386304);
    float*          P        = (float*)         (ws + 18677760);
    float*          partL    = (float*)         (ws + 37093376);
    float*          partO    = (float*)         (ws + 37355520);
    unsigned short* kvn_bf   = (unsigned short*)(ws + 54132736);
    unsigned short* kp       = (unsigned short*)(ws + 87687168);
    unsigned short* vt       = (unsigned short*)(ws + 121241600);

    // 48 KiB dynamic LDS for the fused gemm_kv (3 blocks/CU: 144 <= 160 KiB).
    static bool attr_set = false;
    if (!attr_set) {
        hipFuncSetAttribute(reinterpret_cast<const void*>(gemm_kv_kernel),
                            hipFuncAttributeMaxDynamicSharedMemorySize, 49152);
        attr_set = true;
    }

    // --- prep (fused: ln_kv | wconv | hilo_w | mpack | ln_q) ---
    prep_kernel<<<8832, 256, 0, stream>>>(
        kv, g_kv, b_kv, kvn_bf,
        q,  g_q,  b_q,  qn_bf,
        in_w, wfull_bf,
        out_w, wout_cat,
        mask, mpackp);

    // --- FUSED: K|V projection [0,1024) + Q-proj split-K [1024,2048) ---
    gemm_kv_kernel<<<dim3(2048), 512, 49152, stream>>>(
        kvn_bf, wfull_bf + (size_t)D_*D_, in_b + D_, kp, vt,
        qn_bf, wfull_bf, P);

    // --- MFMA flash attention (XCD-grouped, NCH=2; Q-reduce folded in) ---
    flash_kernel<<<dim3(4*H_*B_*NCH_), 256, 0, stream>>>(
        P, in_b, kp, vt, mpackp, partO, partL);

    // --- Output projection: fused combine+hi/lo, then split-K MFMA ---
    hilo_a_kernel<<<MP_, 256, 0, stream>>>(partO, partL, ctx_cat);
    gemm_splitk_kernel<<<dim3(D_/64, MP_/64, 8), 256, 0, stream>>>(
        ctx_cat, wout_cat, P, 3*D_, 384);
    reduce_kernel<<<B_*NQ_*D_/4/256, 256, 0, stream>>>(P, out_b, out, 8);
}